// Round 4
// baseline (68.909 us; speedup 1.0000x reference)
//
#include <hip/hip_runtime.h>
#include <stdint.h>

#define B_SZ    8
#define N_PTS   4096
#define C_IN    64
#define C_OUT   64
#define KNN     16
#define ROWS    (B_SZ * N_PTS)      // 32768

// ---------------------------------------------------------------------------
// Kernel 0: weight prep.  wcT[c][o] = W1[o][c]-W2[o][c],  w2T[c][o] = W2[o][c]
// ---------------------------------------------------------------------------
__global__ void wprep_kernel(const float* __restrict__ w,
                             float* __restrict__ wcT,
                             float* __restrict__ w2T)
{
    const int id = blockIdx.x * 256 + threadIdx.x;   // (c,o)
    if (id < C_IN * C_OUT) {
        const int c = id >> 6, o = id & 63;
        const float w1 = w[o * 128 + c];
        const float w2 = w[o * 128 + 64 + c];
        wcT[c * 64 + o] = w1 - w2;
        w2T[c * 64 + o] = w2;
    }
}

// ---------------------------------------------------------------------------
// Kernel 1: per-point projections, throughput version.
//   cbuf[r][o] = x[r]·(W1[o]-W2[o]) + bias[o],  nbuf[r][o] = x[r]·W2[o]
// 256 threads / block: stage 64 x-rows in LDS (coalesced float4), each wave
// computes 16 rows; x read back as ds_read_b128 broadcast (uniform address,
// conflict-free), 128 FMAs/row on two interleaved chains (hides FMA latency).
// Weights (128 VGPRs) loaded coalesced from the transposed copies.
// ---------------------------------------------------------------------------
#define PROJ_ROWS 64

__global__ __launch_bounds__(256, 2) void proj_kernel(
    const float* __restrict__ x,
    const float* __restrict__ wcT,
    const float* __restrict__ w2T,
    const float* __restrict__ bias,
    float* __restrict__ cbuf,
    float* __restrict__ nbuf)
{
    __shared__ float xs[PROJ_ROWS][C_IN];   // 16 KiB

    const int t    = threadIdx.x;
    const int lane = t & 63;                // output channel o
    const int g    = t >> 6;                // wave 0..3

    float wc[C_IN], w2[C_IN];
#pragma unroll
    for (int c = 0; c < C_IN; ++c) {        // coalesced 256B loads
        wc[c] = wcT[c * 64 + lane];
        w2[c] = w2T[c * 64 + lane];
    }
    const float bv = bias[lane];

    const int batch = blockIdx.x & 7;       // XCD-affine: batch b on XCD b
    const int chunk = blockIdx.x >> 3;      // 0..63
    const int r0 = batch * N_PTS + chunk * PROJ_ROWS;

    // stage 64 rows (16 KiB) with coalesced float4 loads
    {
        const float4* xv  = (const float4*)(x + (size_t)r0 * C_IN);
        float4*       xsv = (float4*)&xs[0][0];
#pragma unroll
        for (int rnd = 0; rnd < 4; ++rnd)
            xsv[rnd * 256 + t] = xv[rnd * 256 + t];
    }
    __syncthreads();

    for (int i = 0; i < 16; ++i) {
        const int rl = g * 16 + i;
        const int r  = r0 + rl;
        float a1 = bv, a2 = 0.f;
#pragma unroll
        for (int c4 = 0; c4 < 16; ++c4) {
            const float4 xq = *(const float4*)&xs[rl][c4 * 4];  // broadcast b128
            a1 = fmaf(xq.x, wc[c4*4+0], a1);  a2 = fmaf(xq.x, w2[c4*4+0], a2);
            a1 = fmaf(xq.y, wc[c4*4+1], a1);  a2 = fmaf(xq.y, w2[c4*4+1], a2);
            a1 = fmaf(xq.z, wc[c4*4+2], a1);  a2 = fmaf(xq.z, w2[c4*4+2], a2);
            a1 = fmaf(xq.w, wc[c4*4+3], a1);  a2 = fmaf(xq.w, w2[c4*4+3], a2);
        }
        cbuf[(size_t)r * C_OUT + lane] = a1;    // coalesced 256B
        nbuf[(size_t)r * C_OUT + lane] = a2;
    }
}

// ---------------------------------------------------------------------------
// Kernel 2: gather + max + relu + transposed store (unchanged from round 2).
//   out[b][o][n] = relu( cbuf[b,n][o] + max_k nbuf[b, idx[b,n,k]][o] )
// ---------------------------------------------------------------------------
__global__ __launch_bounds__(256) void gather_max_kernel(
    const float* __restrict__ cbuf,
    const float* __restrict__ nbuf,
    const int* __restrict__ eidx,
    float* __restrict__ out)
{
    __shared__ float tile[64][65];

    const int t    = threadIdx.x;
    const int lane = t & 63;
    const int g    = t >> 6;                // wave 0..3
    const int b    = blockIdx.x & 7;        // batch == XCD
    const int tn   = blockIdx.x >> 3;       // 0..63
    const int n0   = tn * 64;

    const float* nb  = nbuf + (size_t)b * N_PTS * C_OUT;
    const int    o4  = (lane & 15) * 4;
    const int    sub = lane >> 4;

    for (int i = 0; i < 4; ++i) {
        const int rbase = b * N_PTS + n0 + g * 16 + i * 4;
        int myidx = eidx[(size_t)rbase * KNN + lane] & (N_PTS - 1);

        const int r = rbase + sub;
        const float4 cv = *(const float4*)(cbuf + (size_t)r * C_OUT + o4);

        float4 mx = make_float4(-1e30f, -1e30f, -1e30f, -1e30f);
#pragma unroll
        for (int k = 0; k < KNN; ++k) {
            const int idx = __shfl(myidx, (lane & 48) | k);
            const float4 v = *(const float4*)(nb + (size_t)idx * C_OUT + o4);
            mx.x = fmaxf(mx.x, v.x);
            mx.y = fmaxf(mx.y, v.y);
            mx.z = fmaxf(mx.z, v.z);
            mx.w = fmaxf(mx.w, v.w);
        }

        const int nl = g * 16 + i * 4 + sub;
        tile[nl][o4 + 0] = fmaxf(cv.x + mx.x, 0.f);
        tile[nl][o4 + 1] = fmaxf(cv.y + mx.y, 0.f);
        tile[nl][o4 + 2] = fmaxf(cv.z + mx.z, 0.f);
        tile[nl][o4 + 3] = fmaxf(cv.w + mx.w, 0.f);
    }

    __syncthreads();

    float* ob = out + (size_t)b * C_OUT * N_PTS + n0;
#pragma unroll
    for (int j = 0; j < 16; ++j) {
        const int o = g * 16 + j;
        ob[(size_t)o * N_PTS + lane] = tile[lane][o];
    }
}

// ---------------------------------------------------------------------------
extern "C" void kernel_launch(void* const* d_in, const int* in_sizes, int n_in,
                              void* d_out, int out_size, void* d_ws, size_t ws_size,
                              hipStream_t stream)
{
    const float* x    = (const float*)d_in[0];
    const int*   eidx = (const int*)d_in[1];    // int64 in ref -> int32 here
    const float* w    = (const float*)d_in[2];  // (64, 128)
    const float* bias = (const float*)d_in[3];  // (64,)
    float*       out  = (float*)d_out;          // (8, 64, 64, 64) f32

    float* cbuf = (float*)d_ws;                        // 8 MiB
    float* nbuf = cbuf + (size_t)ROWS * C_OUT;         // 8 MiB
    float* wcT  = nbuf + (size_t)ROWS * C_OUT;         // 16 KiB
    float* w2T  = wcT + C_IN * C_OUT;                  // 16 KiB

    wprep_kernel<<<16, 256, 0, stream>>>(w, wcT, w2T);
    proj_kernel<<<ROWS / PROJ_ROWS, 256, 0, stream>>>(x, wcT, w2T, bias, cbuf, nbuf);
    gather_max_kernel<<<B_SZ * (N_PTS / 64), 256, 0, stream>>>(cbuf, nbuf, eidx, out);
}

// Round 5
// 30.901 us; speedup vs baseline: 2.2300x; 2.2300x over previous
//
#include <hip/hip_runtime.h>
#include <stdint.h>

#define B_SZ    8
#define N_PTS   4096
#define C_IN    64
#define C_OUT   64
#define KNN     16
#define ROWS    (B_SZ * N_PTS)      // 32768

// ---------------------------------------------------------------------------
// Kernel 0: weight prep.  wcT[c][o] = W1[o][c]-W2[o][c],  w2T[c][o] = W2[o][c]
// ---------------------------------------------------------------------------
__global__ void wprep_kernel(const float* __restrict__ w,
                             float* __restrict__ wcT,
                             float* __restrict__ w2T)
{
    const int id = blockIdx.x * 256 + threadIdx.x;   // (c,o)
    if (id < C_IN * C_OUT) {
        const int c = id >> 6, o = id & 63;
        const float w1 = w[o * 128 + c];
        const float w2 = w[o * 128 + 64 + c];
        wcT[c * 64 + o] = w1 - w2;
        w2T[c * 64 + o] = w2;
    }
}

// ---------------------------------------------------------------------------
// Kernel 1: projections. ANTI-SPILL layout: each wave holds only ONE 64-float
// weight set (VGPR ~85, no scratch):
//   waves 0,1 -> cbuf = x·(W1-W2)+bias   waves 2,3 -> nbuf = x·W2
// 32 rows/block staged in LDS; rows read as broadcast ds_read_b128
// (uniform addr = conflict-free); 2-row interleave = 2 indep FMA chains.
// ---------------------------------------------------------------------------
#define PR 32   // rows per block

__global__ __launch_bounds__(256, 2) void proj_kernel(
    const float* __restrict__ x,
    const float* __restrict__ wcT,
    const float* __restrict__ w2T,
    const float* __restrict__ bias,
    float* __restrict__ cbuf,
    float* __restrict__ nbuf)
{
    __shared__ float xs[PR][C_IN];          // 8 KiB

    const int t    = threadIdx.x;
    const int lane = t & 63;                // output channel o
    const int g    = t >> 6;                // wave 0..3

    const int batch = blockIdx.x & 7;       // XCD-affine
    const int chunk = blockIdx.x >> 3;      // 0..127
    const int r0 = batch * N_PTS + chunk * PR;

    // stage 32 rows (8 KiB) coalesced
    {
        const float4* xv  = (const float4*)(x + (size_t)r0 * C_IN);
        float4*       xsv = (float4*)&xs[0][0];
        xsv[t]       = xv[t];
        xsv[t + 256] = xv[t + 256];
    }

    // per-wave role: weights + bias + destination
    const float* wt = (g < 2) ? wcT : w2T;
    float wreg[C_IN];
#pragma unroll
    for (int c = 0; c < C_IN; ++c)          // coalesced 256B loads
        wreg[c] = wt[c * 64 + lane];
    const float b0   = (g < 2) ? bias[lane] : 0.f;
    float*      obuf = (g < 2) ? cbuf : nbuf;
    const int   rb   = (g & 1) * 16;        // waves 0,2: rows 0-15; 1,3: 16-31

    __syncthreads();

#pragma unroll
    for (int i = 0; i < 8; ++i) {
        const int rA = rb + 2 * i, rB = rA + 1;
        float aA = b0, aB = b0;
#pragma unroll
        for (int c4 = 0; c4 < 16; ++c4) {
            const float4 qA = *(const float4*)&xs[rA][c4 * 4];
            const float4 qB = *(const float4*)&xs[rB][c4 * 4];
            aA = fmaf(qA.x, wreg[c4*4+0], aA);  aB = fmaf(qB.x, wreg[c4*4+0], aB);
            aA = fmaf(qA.y, wreg[c4*4+1], aA);  aB = fmaf(qB.y, wreg[c4*4+1], aB);
            aA = fmaf(qA.z, wreg[c4*4+2], aA);  aB = fmaf(qB.z, wreg[c4*4+2], aB);
            aA = fmaf(qA.w, wreg[c4*4+3], aA);  aB = fmaf(qB.w, wreg[c4*4+3], aB);
        }
        obuf[(size_t)(r0 + rA) * C_OUT + lane] = aA;   // coalesced 256B
        obuf[(size_t)(r0 + rB) * C_OUT + lane] = aB;
    }
}

// ---------------------------------------------------------------------------
// Kernel 2: gather + max + relu + transposed store (unchanged).
//   out[b][o][n] = relu( cbuf[b,n][o] + max_k nbuf[b, idx[b,n,k]][o] )
// ---------------------------------------------------------------------------
__global__ __launch_bounds__(256) void gather_max_kernel(
    const float* __restrict__ cbuf,
    const float* __restrict__ nbuf,
    const int* __restrict__ eidx,
    float* __restrict__ out)
{
    __shared__ float tile[64][65];

    const int t    = threadIdx.x;
    const int lane = t & 63;
    const int g    = t >> 6;                // wave 0..3
    const int b    = blockIdx.x & 7;        // batch == XCD
    const int tn   = blockIdx.x >> 3;       // 0..63
    const int n0   = tn * 64;

    const float* nb  = nbuf + (size_t)b * N_PTS * C_OUT;
    const int    o4  = (lane & 15) * 4;
    const int    sub = lane >> 4;

    for (int i = 0; i < 4; ++i) {
        const int rbase = b * N_PTS + n0 + g * 16 + i * 4;
        int myidx = eidx[(size_t)rbase * KNN + lane] & (N_PTS - 1);

        const int r = rbase + sub;
        const float4 cv = *(const float4*)(cbuf + (size_t)r * C_OUT + o4);

        float4 mx = make_float4(-1e30f, -1e30f, -1e30f, -1e30f);
#pragma unroll
        for (int k = 0; k < KNN; ++k) {
            const int idx = __shfl(myidx, (lane & 48) | k);
            const float4 v = *(const float4*)(nb + (size_t)idx * C_OUT + o4);
            mx.x = fmaxf(mx.x, v.x);
            mx.y = fmaxf(mx.y, v.y);
            mx.z = fmaxf(mx.z, v.z);
            mx.w = fmaxf(mx.w, v.w);
        }

        const int nl = g * 16 + i * 4 + sub;
        tile[nl][o4 + 0] = fmaxf(cv.x + mx.x, 0.f);
        tile[nl][o4 + 1] = fmaxf(cv.y + mx.y, 0.f);
        tile[nl][o4 + 2] = fmaxf(cv.z + mx.z, 0.f);
        tile[nl][o4 + 3] = fmaxf(cv.w + mx.w, 0.f);
    }

    __syncthreads();

    float* ob = out + (size_t)b * C_OUT * N_PTS + n0;
#pragma unroll
    for (int j = 0; j < 16; ++j) {
        const int o = g * 16 + j;
        ob[(size_t)o * N_PTS + lane] = tile[lane][o];
    }
}

// ---------------------------------------------------------------------------
extern "C" void kernel_launch(void* const* d_in, const int* in_sizes, int n_in,
                              void* d_out, int out_size, void* d_ws, size_t ws_size,
                              hipStream_t stream)
{
    const float* x    = (const float*)d_in[0];
    const int*   eidx = (const int*)d_in[1];    // int64 in ref -> int32 here
    const float* w    = (const float*)d_in[2];  // (64, 128)
    const float* bias = (const float*)d_in[3];  // (64,)
    float*       out  = (float*)d_out;          // (8, 64, 64, 64) f32

    float* cbuf = (float*)d_ws;                        // 8 MiB
    float* nbuf = cbuf + (size_t)ROWS * C_OUT;         // 8 MiB
    float* wcT  = nbuf + (size_t)ROWS * C_OUT;         // 16 KiB
    float* w2T  = wcT + C_IN * C_OUT;                  // 16 KiB

    wprep_kernel<<<16, 256, 0, stream>>>(w, wcT, w2T);
    proj_kernel<<<ROWS / PR, 256, 0, stream>>>(x, wcT, w2T, bias, cbuf, nbuf);
    gather_max_kernel<<<B_SZ * (N_PTS / 64), 256, 0, stream>>>(cbuf, nbuf, eidx, out);
}